// Round 12
// baseline (592.184 us; speedup 1.0000x reference)
//
#include <hip/hip_runtime.h>
#include <cstdint>

typedef __attribute__((ext_vector_type(8))) short short8;
typedef __attribute__((ext_vector_type(4))) float f32x4;

__device__ __forceinline__ unsigned short f2bf(float f) {
    uint32_t u = __builtin_bit_cast(uint32_t, f);
    u += 0x7FFFu + ((u >> 16) & 1u);   // round-to-nearest-even
    return (unsigned short)(u >> 16);
}

// out float offsets: Gii 0, Gti 16384, gt 67125248, obj 67649536
// ws bytes [0,32768) = Wt bf16 swizzled; [32768,65536) = Qt bf16 swizzled
// swizzle: byte = (c*256 + k*2) ^ ((c&7)<<4)

// ---------------------------------------------------------------------------
// kS: FUSED setup. ONE block, 512 threads, all phases LDS/register-resident.
//  P0: G = V V^T/128*e^s -> rB regs + out[Gii]
//  P1: dual LDL^T (rA=K, rB=G) + Gauss-Jordan rX = Lunit^-1   (proven loop)
//  P2: rM1 = X^T D^-1 X          (2 k-half passes, X staged via SBIG)
//  P3: rY = G*M1 -> Wt bf16      (4 m-passes: G colblk SBIG + M1 rowblk SMED)
//  P4: rQ = M1*Y - M1 -> Qt bf16 (4 m-passes: M1 colblk SBIG + Y rowblk SMED)
//  trace, logdets, obj.
// Thread (ty,tx): rows I0=ty*8..+7, cols J0=tx*4..+3 of every 128x128 matrix.
// ---------------------------------------------------------------------------
__global__ __launch_bounds__(512, 2) void kS_setup(
    const float* __restrict__ Kii, const float* __restrict__ V,
    const float* __restrict__ gscale, const int* __restrict__ dofp,
    float* __restrict__ out, char* __restrict__ wsb)
{
    __shared__ float colA[2][128], colB[2][128], rowX[2][128];
    __shared__ float sDk[128], sDg[128], srd[128];
    __shared__ float sRed[4], sTr[8];
    __shared__ float SBIG[8448];   // P2: X-half [64][132] ; P3/P4: colblock [128][36]
    __shared__ float SMED[4224];   // P3/P4: rowblock [32][132]

    const int tid = threadIdx.x;
    const int ty = tid >> 5, tx = tid & 31;
    const int I0 = ty * 8, J0 = tx * 4;

    // ---- P0: G = V V^T /128 * e^s -> rB + out[Gii] ----
    f32x4 rB[8];
    {
        const float egs = expf(gscale[0]) * (1.0f / 128.0f);
        const f32x4* V4 = (const f32x4*)V;
        float acc[8][4] = {};
        for (int q = 0; q < 32; ++q) {
            f32x4 vc[4];
            #pragma unroll
            for (int e = 0; e < 4; ++e) vc[e] = V4[(J0 + e) * 32 + q];
            #pragma unroll
            for (int r = 0; r < 8; ++r) {
                const f32x4 vr = V4[(I0 + r) * 32 + q];
                #pragma unroll
                for (int e = 0; e < 4; ++e)
                    acc[r][e] += vr[0]*vc[e][0] + vr[1]*vc[e][1]
                               + vr[2]*vc[e][2] + vr[3]*vc[e][3];
            }
        }
        #pragma unroll
        for (int r = 0; r < 8; ++r) {
            const f32x4 g = { acc[r][0]*egs, acc[r][1]*egs, acc[r][2]*egs, acc[r][3]*egs };
            rB[r] = g;
            *(f32x4*)&out[(I0 + r) * 128 + J0] = g;
        }
    }

    // ---- P1: dual LDL^T + GJ (verbatim proven loop) ----
    f32x4 rA[8], rX[8];
    #pragma unroll
    for (int r = 0; r < 8; ++r) {
        rA[r] = *(const f32x4*)&Kii[(size_t)(I0 + r) * 128 + J0];
        f32x4 z = {0.f, 0.f, 0.f, 0.f};
        #pragma unroll
        for (int e = 0; e < 4; ++e) z[e] = (I0 + r == J0 + e) ? 1.0f : 0.0f;
        rX[r] = z;
    }
    if (tx == 0) {
        #pragma unroll
        for (int r = 0; r < 8; ++r) { colA[0][I0 + r] = rA[r][0]; colB[0][I0 + r] = rB[r][0]; }
    }
    if (ty == 0) {
        #pragma unroll
        for (int e = 0; e < 4; ++e) rowX[0][J0 + e] = rX[0][e];
    }
    __syncthreads();

    for (int k = 0; k < 127; ++k) {
        const int b = k & 1;
        const float dK = colA[b][k], dG = colB[b][k];
        const float rdK = 1.0f / dK, rdG = 1.0f / dG;
        if (tid == 0) { sDk[k] = dK; sDg[k] = dG; }

        f32x4 caj = *(const f32x4*)&colA[b][J0];
        f32x4 cbj = *(const f32x4*)&colB[b][J0];
        const f32x4 xj = *(const f32x4*)&rowX[b][J0];
        #pragma unroll
        for (int e = 0; e < 4; ++e)
            if (J0 + e <= k) { caj[e] = 0.0f; cbj[e] = 0.0f; }

        f32x4 ca0 = *(const f32x4*)&colA[b][I0];
        f32x4 ca1 = *(const f32x4*)&colA[b][I0 + 4];
        f32x4 cb0 = *(const f32x4*)&colB[b][I0];
        f32x4 cb1 = *(const f32x4*)&colB[b][I0 + 4];
        #pragma unroll
        for (int r = 0; r < 4; ++r) {
            if (I0 + r <= k)     { ca0[r] = 0.0f; cb0[r] = 0.0f; }
            if (I0 + 4 + r <= k) { ca1[r] = 0.0f; cb1[r] = 0.0f; }
        }

        if (I0 + 7 > k) {
            #pragma unroll
            for (int r = 0; r < 8; ++r) {
                const float am = (r < 4) ? ca0[r & 3] : ca1[r & 3];
                const float bm = (r < 4) ? cb0[r & 3] : cb1[r & 3];
                const float fA = am * rdK;
                const float fB = bm * rdG;
                rA[r] -= fA * caj;
                rB[r] -= fB * cbj;
                rX[r] -= fA * xj;
            }
        }

        const int kn = k + 1, bn = kn & 1;
        if (tx == (kn >> 2)) {
            const int es = kn & 3;
            #pragma unroll
            for (int ee = 0; ee < 4; ++ee) if (ee == es) {
                #pragma unroll
                for (int r = 0; r < 8; ++r) {
                    colA[bn][I0 + r] = rA[r][ee];
                    colB[bn][I0 + r] = rB[r][ee];
                }
            }
        }
        if (ty == (kn >> 3)) {
            const int rs = kn & 7;
            #pragma unroll
            for (int rr = 0; rr < 8; ++rr) if (rr == rs) {
                #pragma unroll
                for (int e = 0; e < 4; ++e) rowX[bn][J0 + e] = rX[rr][e];
            }
        }
        __syncthreads();
    }
    if (tid == 511) { sDk[127] = rA[7][3]; sDg[127] = rB[7][3]; }
    __syncthreads();

    // srd + logdet partials
    if (tid < 128) {
        srd[tid] = 1.0f / sDk[tid];
        float lk = logf(sDk[tid]);
        float lg = logf(sDg[tid]);
        #pragma unroll
        for (int o = 32; o > 0; o >>= 1) { lk += __shfl_xor(lk, o, 64); lg += __shfl_xor(lg, o, 64); }
        if ((tid & 63) == 0) { sRed[(tid >> 6) * 2] = lk; sRed[(tid >> 6) * 2 + 1] = lg; }
    }

    // ---- P2: rM1 = X^T D^-1 X  (2 passes; X upper-zeros make sum maskless) ----
    f32x4 rM1[8] = {};
    for (int kb = 0; kb < 128; kb += 64) {
        __syncthreads();
        if (I0 >= kb && I0 < kb + 64) {
            #pragma unroll
            for (int r = 0; r < 8; ++r)
                *(f32x4*)&SBIG[(I0 - kb + r) * 132 + J0] = rX[r];
        }
        __syncthreads();
        for (int k = 0; k < 64; ++k) {
            const float rd = srd[kb + k];
            const f32x4 xa0 = *(const f32x4*)&SBIG[k * 132 + I0];
            const f32x4 xa1 = *(const f32x4*)&SBIG[k * 132 + I0 + 4];
            f32x4 xb = *(const f32x4*)&SBIG[k * 132 + J0];
            xb *= rd;
            #pragma unroll
            for (int r = 0; r < 4; ++r) {
                rM1[r]     += xa0[r] * xb;
                rM1[r + 4] += xa1[r] * xb;
            }
        }
    }

    // trace = sum(M1 o G) — read own G tile back (own writes, L1-hot)
    {
        float tr = 0.0f;
        #pragma unroll
        for (int r = 0; r < 8; ++r) {
            const f32x4 g = *(const f32x4*)&out[(I0 + r) * 128 + J0];
            tr += rM1[r][0]*g[0] + rM1[r][1]*g[1] + rM1[r][2]*g[2] + rM1[r][3]*g[3];
        }
        #pragma unroll
        for (int o = 32; o > 0; o >>= 1) tr += __shfl_xor(tr, o, 64);
        if ((tid & 63) == 0) sTr[tid >> 6] = tr;
    }

    // ---- P3: rY = G*M1  (4 m-passes) -> Wt bf16 swizzled ----
    f32x4 rY[8] = {};
    for (int mb = 0; mb < 128; mb += 32) {
        __syncthreads();
        // stage G colblock [128][32] -> SBIG stride 36 (from out[Gii], L1/L2-hot)
        for (int v = tid; v < 1024; v += 512) {
            const int row = v >> 3, c4 = (v & 7) * 4;
            const f32x4 g = *(const f32x4*)&out[row * 128 + mb + c4];
            SBIG[row * 36 + c4 + 0] = g[0];
            SBIG[row * 36 + c4 + 1] = g[1];
            SBIG[row * 36 + c4 + 2] = g[2];
            SBIG[row * 36 + c4 + 3] = g[3];
        }
        // stage M1 rowblock [32][128] -> SMED (owner registers)
        if (I0 >= mb && I0 < mb + 32) {
            #pragma unroll
            for (int r = 0; r < 8; ++r)
                *(f32x4*)&SMED[(I0 - mb + r) * 132 + J0] = rM1[r];
        }
        __syncthreads();
        for (int mm = 0; mm < 32; ++mm) {
            const f32x4 m1r = *(const f32x4*)&SMED[mm * 132 + J0];
            #pragma unroll
            for (int r = 0; r < 8; ++r)
                rY[r] += SBIG[(I0 + r) * 36 + mm] * m1r;
        }
    }
    #pragma unroll
    for (int r = 0; r < 8; ++r) {     // Wt[c][k]=Y[c][k]
        const int c = I0 + r;
        const uint32_t lo = (uint32_t)f2bf(rY[r][0]) | ((uint32_t)f2bf(rY[r][1]) << 16);
        const uint32_t hi = (uint32_t)f2bf(rY[r][2]) | ((uint32_t)f2bf(rY[r][3]) << 16);
        const uint32_t byteoff = (uint32_t)((c * 256 + J0 * 2) ^ ((c & 7) << 4));
        *(uint2*)(wsb + byteoff) = make_uint2(lo, hi);
    }

    // ---- P4: rQ = M1*Y - M1  (4 m-passes) -> Qt bf16 swizzled ----
    f32x4 rQ[8];
    #pragma unroll
    for (int r = 0; r < 8; ++r) rQ[r] = -rM1[r];
    for (int mb = 0; mb < 128; mb += 32) {
        __syncthreads();
        // stage M1 colblock (cols mb..mb+31, all rows) from owner registers
        if (J0 >= mb && J0 < mb + 32) {
            #pragma unroll
            for (int r = 0; r < 8; ++r) {
                #pragma unroll
                for (int e = 0; e < 4; ++e)
                    SBIG[(I0 + r) * 36 + (J0 - mb) + e] = rM1[r][e];
            }
        }
        // stage Y rowblock from owner registers
        if (I0 >= mb && I0 < mb + 32) {
            #pragma unroll
            for (int r = 0; r < 8; ++r)
                *(f32x4*)&SMED[(I0 - mb + r) * 132 + J0] = rY[r];
        }
        __syncthreads();
        for (int mm = 0; mm < 32; ++mm) {
            const f32x4 yr = *(const f32x4*)&SMED[mm * 132 + J0];
            #pragma unroll
            for (int r = 0; r < 8; ++r)
                rQ[r] += SBIG[(I0 + r) * 36 + mm] * yr;
        }
    }
    #pragma unroll
    for (int r = 0; r < 8; ++r) {
        const int c = I0 + r;
        const uint32_t lo = (uint32_t)f2bf(rQ[r][0]) | ((uint32_t)f2bf(rQ[r][1]) << 16);
        const uint32_t hi = (uint32_t)f2bf(rQ[r][2]) | ((uint32_t)f2bf(rQ[r][3]) << 16);
        const uint32_t byteoff = (uint32_t)((c * 256 + J0 * 2) ^ ((c & 7) << 4));
        *(uint2*)(wsb + 32768 + byteoff) = make_uint2(lo, hi);
    }

    // ---- obj ----
    __syncthreads();
    if (tid == 0) {
        float trace = 0.0f;
        #pragma unroll
        for (int i = 0; i < 8; ++i) trace += sTr[i];
        const float ldK = sRed[0] + sRed[2];
        const float ldG = sRed[1] + sRed[3];
        const float dof = (float)dofp[0];
        out[67649536] = -0.5f * dof * (-(ldG - ldK) + trace - 128.0f);
    }
}

// ---------------------------------------------------------------------------
// main: Gti = T*W, gt = tt + rowsum((T*Q) o T).  (verbatim R4 winner, ~175us)
// 256 rows/block, 512 threads (8 waves), 2048 blocks, 64KB LDS.
// All T-loads issued up front (one latency exposure); direct Gti stores.
// ---------------------------------------------------------------------------
__global__ __launch_bounds__(512) void main_kernel(
    const float* __restrict__ Kti, const float* __restrict__ Kt,
    const float* __restrict__ ws, float* __restrict__ Gti,
    float* __restrict__ gt)
{
    __shared__ __align__(16) char smem[65536];   // Wt|Qt bf16 swizzled image
    const int tid = threadIdx.x;
    const int lane = tid & 63, wid = tid >> 6;
    const int l15 = lane & 15, l4 = lane >> 4;
    const int brow = blockIdx.x * 256;
    const int wrow = wid * 32;

    const float* tbase = Kti + (size_t)(brow + wrow + l15) * 128;

    // 1) issue ALL 16 T-loads (256 B/lane in flight, one vmcnt drain)
    f32x4 t[4][4];
    #pragma unroll
    for (int kc = 0; kc < 4; ++kc) {
        const float* p0 = tbase + kc * 32 + l4 * 8;
        const float* p1 = p0 + 16 * 128;
        t[kc][0] = *(const f32x4*)p0;
        t[kc][1] = *(const f32x4*)(p0 + 4);
        t[kc][2] = *(const f32x4*)p1;
        t[kc][3] = *(const f32x4*)(p1 + 4);
    }

    // 2) stage ws -> LDS (L2/L3-hot), 128 B/thread
    {
        f32x4* s4 = (f32x4*)smem;
        const f32x4* w4 = (const f32x4*)ws;
        #pragma unroll
        for (int i = 0; i < 8; ++i) s4[tid + i * 512] = w4[tid + i * 512];
    }

    // 3) convert T to bf16 A-frags (waits the global loads)
    short8 a[4][2];
    #pragma unroll
    for (int kc = 0; kc < 4; ++kc) {
        a[kc][0] = { (short)f2bf(t[kc][0][0]), (short)f2bf(t[kc][0][1]), (short)f2bf(t[kc][0][2]), (short)f2bf(t[kc][0][3]),
                     (short)f2bf(t[kc][1][0]), (short)f2bf(t[kc][1][1]), (short)f2bf(t[kc][1][2]), (short)f2bf(t[kc][1][3]) };
        a[kc][1] = { (short)f2bf(t[kc][2][0]), (short)f2bf(t[kc][2][1]), (short)f2bf(t[kc][2][2]), (short)f2bf(t[kc][2][3]),
                     (short)f2bf(t[kc][3][0]), (short)f2bf(t[kc][3][1]), (short)f2bf(t[kc][3][2]), (short)f2bf(t[kc][3][3]) };
    }
    __syncthreads();

    // 4) uninterrupted 128-MFMA stream
    f32x4 accW[2][8] = {};
    f32x4 accZ[2][8] = {};
    #pragma unroll
    for (int kc = 0; kc < 4; ++kc) {
        const int k0 = kc * 32 + l4 * 8;
        #pragma unroll
        for (int ct = 0; ct < 8; ++ct) {
            const int c = ct * 16 + l15;
            const int byteoff = (c * 256 + k0 * 2) ^ ((c & 7) << 4);
            const short8 bW = *(const short8*)(smem + byteoff);
            const short8 bQ = *(const short8*)(smem + 32768 + byteoff);
            accW[0][ct] = __builtin_amdgcn_mfma_f32_16x16x32_bf16(a[kc][0], bW, accW[0][ct], 0, 0, 0);
            accW[1][ct] = __builtin_amdgcn_mfma_f32_16x16x32_bf16(a[kc][1], bW, accW[1][ct], 0, 0, 0);
            accZ[0][ct] = __builtin_amdgcn_mfma_f32_16x16x32_bf16(a[kc][0], bQ, accZ[0][ct], 0, 0, 0);
            accZ[1][ct] = __builtin_amdgcn_mfma_f32_16x16x32_bf16(a[kc][1], bQ, accZ[1][ct], 0, 0, 0);
        }
    }

    // 5) gt epilogue (C/D layout: col=l15, row=l4*4+r); trow re-reads L1/L2-hot
    #pragma unroll
    for (int rt = 0; rt < 2; ++rt) {
        #pragma unroll
        for (int r = 0; r < 4; ++r) {
            const int row = brow + wrow + rt * 16 + l4 * 4 + r;
            const float* trow = Kti + (size_t)row * 128;
            float p = 0.0f;
            #pragma unroll
            for (int ct = 0; ct < 8; ++ct) p += accZ[rt][ct][r] * trow[ct * 16 + l15];
            p += __shfl_xor(p, 1, 64);
            p += __shfl_xor(p, 2, 64);
            p += __shfl_xor(p, 4, 64);
            p += __shfl_xor(p, 8, 64);
            if (l15 == 0) gt[row] = Kt[row] + p;
        }
    }

    // 6) direct Gti stores from accW (16-lane / 64B coalesced granules)
    #pragma unroll
    for (int rt = 0; rt < 2; ++rt) {
        #pragma unroll
        for (int r = 0; r < 4; ++r) {
            float* grow = Gti + (size_t)(brow + wrow + rt * 16 + l4 * 4 + r) * 128 + l15;
            #pragma unroll
            for (int ct = 0; ct < 8; ++ct)
                grow[ct * 16] = accW[rt][ct][r];
        }
    }
}

extern "C" void kernel_launch(void* const* d_in, const int* in_sizes, int n_in,
                              void* d_out, int out_size, void* d_ws, size_t ws_size,
                              hipStream_t stream)
{
    const float* Kii = (const float*)d_in[0];
    const float* Kti = (const float*)d_in[1];
    const float* Kt  = (const float*)d_in[2];
    const float* V   = (const float*)d_in[3];
    const float* gs  = (const float*)d_in[4];
    const int*   dof = (const int*)d_in[5];
    float* out = (float*)d_out;
    float* ws  = (float*)d_ws;

    const int N = in_sizes[2];          // 524288
    const int nblocks = N / 256;        // 2048

    kS_setup<<<1, 512, 0, stream>>>(Kii, V, gs, dof, out, (char*)ws);
    main_kernel<<<nblocks, 512, 0, stream>>>(Kti, Kt, ws,
                                             out + 16384,          // Gti
                                             out + 67125248);      // gt
}

// Round 13
// 350.052 us; speedup vs baseline: 1.6917x; 1.6917x over previous
//
#include <hip/hip_runtime.h>
#include <cstdint>

typedef __attribute__((ext_vector_type(8))) short short8;
typedef __attribute__((ext_vector_type(4))) float f32x4;

__device__ __forceinline__ unsigned short f2bf(float f) {
    uint32_t u = __builtin_bit_cast(uint32_t, f);
    u += 0x7FFFu + ((u >> 16) & 1u);   // round-to-nearest-even
    return (unsigned short)(u >> 16);
}

// out float offsets: Gii 0, Gti 16384, gt 67125248, obj 67649536
// fp32 scratch INSIDE the Gti region (overwritten later by main):
#define SX_OFF   65536     // X = Lunit^-1 (unit lower, upper zeros)
#define SD_OFF   81920     // d[0..127], [128]=logdetK, [129]=logdetG
// ws bytes [0,32768) = Wt bf16 swizzled; [32768,65536) = Qt bf16 swizzled
// swizzle: byte = (c*256 + k*2) ^ ((c&7)<<4)

// ---------------------------------------------------------------------------
// kA: ONE block, 512 threads. P0: G = V V^T/128*e^s -> rB + out[Gii].
// P1: dual LDL^T (K,G) + Gauss-Jordan X = Lunit^-1 (proven loop).
// Epilogue: X -> global, d[], logdets. Live set rA+rB+rX = 96 regs only.
// ---------------------------------------------------------------------------
__global__ __launch_bounds__(512, 2) void kA_factor(
    const float* __restrict__ Kii, const float* __restrict__ V,
    const float* __restrict__ gscale, float* __restrict__ out)
{
    __shared__ float colA[2][128], colB[2][128], rowX[2][128];
    __shared__ float sDk[128], sDg[128], sRed[4];

    const int tid = threadIdx.x;
    const int ty = tid >> 5, tx = tid & 31;
    const int I0 = ty * 8, J0 = tx * 4;
    float* sX = out + SX_OFF;
    float* dbuf = out + SD_OFF;

    // ---- P0: G = V V^T /128 * e^s -> rB + out[Gii] ----
    f32x4 rB[8];
    {
        const float egs = expf(gscale[0]) * (1.0f / 128.0f);
        const f32x4* V4 = (const f32x4*)V;
        float acc[8][4] = {};
        for (int q = 0; q < 32; ++q) {
            f32x4 vc[4];
            #pragma unroll
            for (int e = 0; e < 4; ++e) vc[e] = V4[(J0 + e) * 32 + q];
            #pragma unroll
            for (int r = 0; r < 8; ++r) {
                const f32x4 vr = V4[(I0 + r) * 32 + q];
                #pragma unroll
                for (int e = 0; e < 4; ++e)
                    acc[r][e] += vr[0]*vc[e][0] + vr[1]*vc[e][1]
                               + vr[2]*vc[e][2] + vr[3]*vc[e][3];
            }
        }
        #pragma unroll
        for (int r = 0; r < 8; ++r) {
            const f32x4 g = { acc[r][0]*egs, acc[r][1]*egs, acc[r][2]*egs, acc[r][3]*egs };
            rB[r] = g;
            *(f32x4*)&out[(I0 + r) * 128 + J0] = g;
        }
    }

    // ---- P1: dual LDL^T + GJ ----
    f32x4 rA[8], rX[8];
    #pragma unroll
    for (int r = 0; r < 8; ++r) {
        rA[r] = *(const f32x4*)&Kii[(size_t)(I0 + r) * 128 + J0];
        f32x4 z = {0.f, 0.f, 0.f, 0.f};
        #pragma unroll
        for (int e = 0; e < 4; ++e) z[e] = (I0 + r == J0 + e) ? 1.0f : 0.0f;
        rX[r] = z;
    }
    if (tx == 0) {
        #pragma unroll
        for (int r = 0; r < 8; ++r) { colA[0][I0 + r] = rA[r][0]; colB[0][I0 + r] = rB[r][0]; }
    }
    if (ty == 0) {
        #pragma unroll
        for (int e = 0; e < 4; ++e) rowX[0][J0 + e] = rX[0][e];
    }
    __syncthreads();

    for (int k = 0; k < 127; ++k) {
        const int b = k & 1;
        const float dK = colA[b][k], dG = colB[b][k];
        const float rdK = 1.0f / dK, rdG = 1.0f / dG;
        if (tid == 0) { sDk[k] = dK; sDg[k] = dG; }

        f32x4 caj = *(const f32x4*)&colA[b][J0];
        f32x4 cbj = *(const f32x4*)&colB[b][J0];
        const f32x4 xj = *(const f32x4*)&rowX[b][J0];
        #pragma unroll
        for (int e = 0; e < 4; ++e)
            if (J0 + e <= k) { caj[e] = 0.0f; cbj[e] = 0.0f; }

        f32x4 ca0 = *(const f32x4*)&colA[b][I0];
        f32x4 ca1 = *(const f32x4*)&colA[b][I0 + 4];
        f32x4 cb0 = *(const f32x4*)&colB[b][I0];
        f32x4 cb1 = *(const f32x4*)&colB[b][I0 + 4];
        #pragma unroll
        for (int r = 0; r < 4; ++r) {
            if (I0 + r <= k)     { ca0[r] = 0.0f; cb0[r] = 0.0f; }
            if (I0 + 4 + r <= k) { ca1[r] = 0.0f; cb1[r] = 0.0f; }
        }

        if (I0 + 7 > k) {
            #pragma unroll
            for (int r = 0; r < 8; ++r) {
                const float am = (r < 4) ? ca0[r & 3] : ca1[r & 3];
                const float bm = (r < 4) ? cb0[r & 3] : cb1[r & 3];
                const float fA = am * rdK;
                const float fB = bm * rdG;
                rA[r] -= fA * caj;
                rB[r] -= fB * cbj;
                rX[r] -= fA * xj;
            }
        }

        const int kn = k + 1, bn = kn & 1;
        if (tx == (kn >> 2)) {
            const int es = kn & 3;
            #pragma unroll
            for (int ee = 0; ee < 4; ++ee) if (ee == es) {
                #pragma unroll
                for (int r = 0; r < 8; ++r) {
                    colA[bn][I0 + r] = rA[r][ee];
                    colB[bn][I0 + r] = rB[r][ee];
                }
            }
        }
        if (ty == (kn >> 3)) {
            const int rs = kn & 7;
            #pragma unroll
            for (int rr = 0; rr < 8; ++rr) if (rr == rs) {
                #pragma unroll
                for (int e = 0; e < 4; ++e) rowX[bn][J0 + e] = rX[rr][e];
            }
        }
        __syncthreads();
    }
    if (tid == 511) { sDk[127] = rA[7][3]; sDg[127] = rB[7][3]; }

    // epilogue: X dump, d, logdets
    #pragma unroll
    for (int r = 0; r < 8; ++r)
        *(f32x4*)&sX[(I0 + r) * 128 + J0] = rX[r];
    __syncthreads();

    if (tid < 128) {
        dbuf[tid] = sDk[tid];
        float lk = logf(sDk[tid]);
        float lg = logf(sDg[tid]);
        #pragma unroll
        for (int o = 32; o > 0; o >>= 1) { lk += __shfl_xor(lk, o, 64); lg += __shfl_xor(lg, o, 64); }
        if ((tid & 63) == 0) { sRed[(tid >> 6) * 2] = lk; sRed[(tid >> 6) * 2 + 1] = lg; }
    }
    __syncthreads();
    if (tid == 0) {
        dbuf[128] = sRed[0] + sRed[2];   // logdet K
        dbuf[129] = sRed[1] + sRed[3];   // logdet G
    }
}

// ---------------------------------------------------------------------------
// kG: 16 blocks x 256 thr. Each block builds the FULL M1 = X^T D^-1 X in LDS
// (redundant x16 -> zero cross-block deps), then its 8-row strip of:
//   Wt = (G*M1)^T bf16 swizzled ; Z = M1[strip]*G (+ full-trace partial) ;
//   Qt = (Z*M1 - M1[strip]) bf16 swizzled ; block 0 writes obj.
// All inner loops read LDS-resident M1 (conflict-free ds_read_b128).
// ---------------------------------------------------------------------------
__global__ __launch_bounds__(256) void kG_rest(
    float* __restrict__ out, char* __restrict__ wsb, const int* __restrict__ dofp)
{
    __shared__ float M1s[128 * 132];   // 67584 B
    __shared__ float Zs[8 * 132];      // 4224 B
    __shared__ float srd[128];

    const int tid = threadIdx.x;
    const int bid = blockIdx.x;
    const float* Xg = out + SX_OFF;
    const float* dbuf = out + SD_OFF;
    const float* G = out;              // Gii

    if (tid < 128) srd[tid] = 1.0f / dbuf[tid];
    __syncthreads();

    // ---- M1 full (thread: 16 rows x 4 cols) ----
    {
        const int ty = tid >> 5, tx = tid & 31;
        const int I0 = ty * 16, J0 = tx * 4;
        f32x4 acc[16] = {};
        for (int k = 0; k < 128; ++k) {
            f32x4 xb = *(const f32x4*)&Xg[k * 128 + J0];
            xb *= srd[k];
            const f32x4 xa0 = *(const f32x4*)&Xg[k * 128 + I0];
            const f32x4 xa1 = *(const f32x4*)&Xg[k * 128 + I0 + 4];
            const f32x4 xa2 = *(const f32x4*)&Xg[k * 128 + I0 + 8];
            const f32x4 xa3 = *(const f32x4*)&Xg[k * 128 + I0 + 12];
            #pragma unroll
            for (int r = 0; r < 4; ++r) {
                acc[r]      += xa0[r] * xb;
                acc[r + 4]  += xa1[r] * xb;
                acc[r + 8]  += xa2[r] * xb;
                acc[r + 12] += xa3[r] * xb;
            }
        }
        #pragma unroll
        for (int r = 0; r < 16; ++r)
            *(f32x4*)&M1s[(I0 + r) * 132 + J0] = acc[r];
    }
    __syncthreads();

    const int r8 = tid >> 5;           // strip row within block [0,8)
    const int j4 = tid & 31;           // col quad [0,32)
    const int c = bid * 8 + r8;        // global output row

    // ---- Wt strip: Y[c][:] = G[c,:]*M1 ----
    {
        f32x4 y = {0.f, 0.f, 0.f, 0.f};
        const float* grow = G + (size_t)c * 128;
        for (int m = 0; m < 128; ++m)
            y += grow[m] * *(const f32x4*)&M1s[m * 132 + j4 * 4];
        const uint32_t lo = (uint32_t)f2bf(y[0]) | ((uint32_t)f2bf(y[1]) << 16);
        const uint32_t hi = (uint32_t)f2bf(y[2]) | ((uint32_t)f2bf(y[3]) << 16);
        const uint32_t byteoff = (uint32_t)((c * 256 + j4 * 8) ^ ((c & 7) << 4));
        *(uint2*)(wsb + byteoff) = make_uint2(lo, hi);
    }

    // ---- Z strip = M1[c,:]*G ; fused full-trace partial (r8==0 lanes) ----
    float trp = 0.0f;
    {
        f32x4 z = {0.f, 0.f, 0.f, 0.f};
        const f32x4* G4 = (const f32x4*)G;
        for (int m = 0; m < 128; ++m) {
            const f32x4 g = G4[m * 32 + j4];
            z += M1s[c * 132 + m] * g;
            if (r8 == 0) {
                const f32x4 mm = *(const f32x4*)&M1s[m * 132 + j4 * 4];
                trp += mm[0]*g[0] + mm[1]*g[1] + mm[2]*g[2] + mm[3]*g[3];
            }
        }
        *(f32x4*)&Zs[r8 * 132 + j4 * 4] = z;
    }
    __syncthreads();

    // ---- Qt strip: Q[c][:] = Z[r8,:]*M1 - M1[c,:] ----
    {
        f32x4 q = - *(const f32x4*)&M1s[c * 132 + j4 * 4];
        for (int m = 0; m < 128; ++m)
            q += Zs[r8 * 132 + m] * *(const f32x4*)&M1s[m * 132 + j4 * 4];
        const uint32_t lo = (uint32_t)f2bf(q[0]) | ((uint32_t)f2bf(q[1]) << 16);
        const uint32_t hi = (uint32_t)f2bf(q[2]) | ((uint32_t)f2bf(q[3]) << 16);
        const uint32_t byteoff = (uint32_t)((c * 256 + j4 * 8) ^ ((c & 7) << 4));
        *(uint2*)(wsb + 32768 + byteoff) = make_uint2(lo, hi);
    }

    // ---- obj: trace reduced over lanes 0..31 of wave 0; block 0 writes ----
    if (r8 == 0) {
        #pragma unroll
        for (int o = 16; o > 0; o >>= 1) trp += __shfl_xor(trp, o, 32);
        if (tid == 0 && bid == 0) {
            const float ldK = dbuf[128], ldG = dbuf[129];
            const float dof = (float)dofp[0];
            out[67649536] = -0.5f * dof * (-(ldG - ldK) + trp - 128.0f);
        }
    }
}

// ---------------------------------------------------------------------------
// main: Gti = T*W, gt = tt + rowsum((T*Q) o T).  (verbatim R4 winner, ~175us)
// 256 rows/block, 512 threads (8 waves), 2048 blocks, 64KB LDS.
// ---------------------------------------------------------------------------
__global__ __launch_bounds__(512) void main_kernel(
    const float* __restrict__ Kti, const float* __restrict__ Kt,
    const float* __restrict__ ws, float* __restrict__ Gti,
    float* __restrict__ gt)
{
    __shared__ __align__(16) char smem[65536];   // Wt|Qt bf16 swizzled image
    const int tid = threadIdx.x;
    const int lane = tid & 63, wid = tid >> 6;
    const int l15 = lane & 15, l4 = lane >> 4;
    const int brow = blockIdx.x * 256;
    const int wrow = wid * 32;

    const float* tbase = Kti + (size_t)(brow + wrow + l15) * 128;

    // 1) issue ALL 16 T-loads (256 B/lane in flight, one vmcnt drain)
    f32x4 t[4][4];
    #pragma unroll
    for (int kc = 0; kc < 4; ++kc) {
        const float* p0 = tbase + kc * 32 + l4 * 8;
        const float* p1 = p0 + 16 * 128;
        t[kc][0] = *(const f32x4*)p0;
        t[kc][1] = *(const f32x4*)(p0 + 4);
        t[kc][2] = *(const f32x4*)p1;
        t[kc][3] = *(const f32x4*)(p1 + 4);
    }

    // 2) stage ws -> LDS (L2/L3-hot), 128 B/thread
    {
        f32x4* s4 = (f32x4*)smem;
        const f32x4* w4 = (const f32x4*)ws;
        #pragma unroll
        for (int i = 0; i < 8; ++i) s4[tid + i * 512] = w4[tid + i * 512];
    }

    // 3) convert T to bf16 A-frags (waits the global loads)
    short8 a[4][2];
    #pragma unroll
    for (int kc = 0; kc < 4; ++kc) {
        a[kc][0] = { (short)f2bf(t[kc][0][0]), (short)f2bf(t[kc][0][1]), (short)f2bf(t[kc][0][2]), (short)f2bf(t[kc][0][3]),
                     (short)f2bf(t[kc][1][0]), (short)f2bf(t[kc][1][1]), (short)f2bf(t[kc][1][2]), (short)f2bf(t[kc][1][3]) };
        a[kc][1] = { (short)f2bf(t[kc][2][0]), (short)f2bf(t[kc][2][1]), (short)f2bf(t[kc][2][2]), (short)f2bf(t[kc][2][3]),
                     (short)f2bf(t[kc][3][0]), (short)f2bf(t[kc][3][1]), (short)f2bf(t[kc][3][2]), (short)f2bf(t[kc][3][3]) };
    }
    __syncthreads();

    // 4) uninterrupted 128-MFMA stream
    f32x4 accW[2][8] = {};
    f32x4 accZ[2][8] = {};
    #pragma unroll
    for (int kc = 0; kc < 4; ++kc) {
        const int k0 = kc * 32 + l4 * 8;
        #pragma unroll
        for (int ct = 0; ct < 8; ++ct) {
            const int c = ct * 16 + l15;
            const int byteoff = (c * 256 + k0 * 2) ^ ((c & 7) << 4);
            const short8 bW = *(const short8*)(smem + byteoff);
            const short8 bQ = *(const short8*)(smem + 32768 + byteoff);
            accW[0][ct] = __builtin_amdgcn_mfma_f32_16x16x32_bf16(a[kc][0], bW, accW[0][ct], 0, 0, 0);
            accW[1][ct] = __builtin_amdgcn_mfma_f32_16x16x32_bf16(a[kc][1], bW, accW[1][ct], 0, 0, 0);
            accZ[0][ct] = __builtin_amdgcn_mfma_f32_16x16x32_bf16(a[kc][0], bQ, accZ[0][ct], 0, 0, 0);
            accZ[1][ct] = __builtin_amdgcn_mfma_f32_16x16x32_bf16(a[kc][1], bQ, accZ[1][ct], 0, 0, 0);
        }
    }

    // 5) gt epilogue (C/D layout: col=l15, row=l4*4+r); trow re-reads L1/L2-hot
    #pragma unroll
    for (int rt = 0; rt < 2; ++rt) {
        #pragma unroll
        for (int r = 0; r < 4; ++r) {
            const int row = brow + wrow + rt * 16 + l4 * 4 + r;
            const float* trow = Kti + (size_t)row * 128;
            float p = 0.0f;
            #pragma unroll
            for (int ct = 0; ct < 8; ++ct) p += accZ[rt][ct][r] * trow[ct * 16 + l15];
            p += __shfl_xor(p, 1, 64);
            p += __shfl_xor(p, 2, 64);
            p += __shfl_xor(p, 4, 64);
            p += __shfl_xor(p, 8, 64);
            if (l15 == 0) gt[row] = Kt[row] + p;
        }
    }

    // 6) direct Gti stores from accW (16-lane / 64B coalesced granules)
    #pragma unroll
    for (int rt = 0; rt < 2; ++rt) {
        #pragma unroll
        for (int r = 0; r < 4; ++r) {
            float* grow = Gti + (size_t)(brow + wrow + rt * 16 + l4 * 4 + r) * 128 + l15;
            #pragma unroll
            for (int ct = 0; ct < 8; ++ct)
                grow[ct * 16] = accW[rt][ct][r];
        }
    }
}

extern "C" void kernel_launch(void* const* d_in, const int* in_sizes, int n_in,
                              void* d_out, int out_size, void* d_ws, size_t ws_size,
                              hipStream_t stream)
{
    const float* Kii = (const float*)d_in[0];
    const float* Kti = (const float*)d_in[1];
    const float* Kt  = (const float*)d_in[2];
    const float* V   = (const float*)d_in[3];
    const float* gs  = (const float*)d_in[4];
    const int*   dof = (const int*)d_in[5];
    float* out = (float*)d_out;
    float* ws  = (float*)d_ws;

    const int N = in_sizes[2];          // 524288
    const int nblocks = N / 256;        // 2048

    kA_factor<<<1, 512, 0, stream>>>(Kii, V, gs, out);
    kG_rest<<<16, 256, 0, stream>>>(out, (char*)ws, dof);
    main_kernel<<<nblocks, 512, 0, stream>>>(Kti, Kt, ws,
                                             out + 16384,          // Gti
                                             out + 67125248);      // gt
}

// Round 14
// 349.464 us; speedup vs baseline: 1.6945x; 1.0017x over previous
//
#include <hip/hip_runtime.h>
#include <cstdint>

typedef __attribute__((ext_vector_type(8))) short short8;
typedef __attribute__((ext_vector_type(4))) float f32x4;

__device__ __forceinline__ unsigned short f2bf(float f) {
    uint32_t u = __builtin_bit_cast(uint32_t, f);
    u += 0x7FFFu + ((u >> 16) & 1u);   // round-to-nearest-even
    return (unsigned short)(u >> 16);
}

// out float offsets: Gii 0, Gti 16384, gt 67125248, obj 67649536
// ws bytes [0,32768) = Wt bf16 swizzled; [32768,65536) = Qt bf16 swizzled
// swizzle: byte = (c*256 + k*2) ^ ((c&7)<<4)

// ---------------------------------------------------------------------------
// kS2: FUSED setup, ONE block x 512 threads. Key design rules (from R2/R7/R12
// failures): (1) no register state carried across phases except the factor
// loop's own 96-reg set; (2) all GEMM-phase operands LDS-resident ([128][132]
// X->Y buffer + [128][132] M1 = 135KB static, R2 precedent); (3) LDS access
// patterns are wave-broadcast or lane-consecutive b128 (conflict-free).
//  P0: G = V V^T/128*e^s -> rB + out[Gii]
//  P1: dual LDL^T (K in rA, G in rB) + Gauss-Jordan rX = Lunit^-1  [proven]
//  P2: LM = M1 = X^T D^-1 X   (reads LX)
//  tr: trace partial from M1 tile (regs) o G tile (own global, L1-hot)
//  P3: Y = G*LM -> LX (X dead) ; Wt bf16 -> ws
//  P4: Q = LM*Y - LM -> Qt bf16 -> ws ; obj
// Thread (ty,tx): rows I0=ty*8..+7, cols J0=tx*4..+3 of each 128x128 matrix.
// ---------------------------------------------------------------------------
__global__ __launch_bounds__(512, 2) void kS2_setup(
    const float* __restrict__ Kii, const float* __restrict__ V,
    const float* __restrict__ gscale, const int* __restrict__ dofp,
    float* __restrict__ out, char* __restrict__ wsb)
{
    __shared__ float LX[128 * 132];    // X, later Y   (67584 B)
    __shared__ float LM[128 * 132];    // M1           (67584 B)
    __shared__ float colA[2][128], colB[2][128], rowX[2][128];
    __shared__ float sDk[128], sDg[128], srd[128];
    __shared__ float sRed[4], sTr[8];

    const int tid = threadIdx.x;
    const int ty = tid >> 5, tx = tid & 31;
    const int I0 = ty * 8, J0 = tx * 4;

    // ---- P0: G = V V^T /128 * e^s -> rB + out[Gii]  (proven in kA) ----
    f32x4 rB[8];
    {
        const float egs = expf(gscale[0]) * (1.0f / 128.0f);
        const f32x4* V4 = (const f32x4*)V;
        float acc[8][4] = {};
        for (int q = 0; q < 32; ++q) {
            f32x4 vc[4];
            #pragma unroll
            for (int e = 0; e < 4; ++e) vc[e] = V4[(J0 + e) * 32 + q];
            #pragma unroll
            for (int r = 0; r < 8; ++r) {
                const f32x4 vr = V4[(I0 + r) * 32 + q];
                #pragma unroll
                for (int e = 0; e < 4; ++e)
                    acc[r][e] += vr[0]*vc[e][0] + vr[1]*vc[e][1]
                               + vr[2]*vc[e][2] + vr[3]*vc[e][3];
            }
        }
        #pragma unroll
        for (int r = 0; r < 8; ++r) {
            const f32x4 g = { acc[r][0]*egs, acc[r][1]*egs, acc[r][2]*egs, acc[r][3]*egs };
            rB[r] = g;
            *(f32x4*)&out[(I0 + r) * 128 + J0] = g;
        }
    }

    // ---- P1: dual LDL^T + GJ (proven loop, verbatim) ----
    f32x4 rA[8], rX[8];
    #pragma unroll
    for (int r = 0; r < 8; ++r) {
        rA[r] = *(const f32x4*)&Kii[(size_t)(I0 + r) * 128 + J0];
        f32x4 z = {0.f, 0.f, 0.f, 0.f};
        #pragma unroll
        for (int e = 0; e < 4; ++e) z[e] = (I0 + r == J0 + e) ? 1.0f : 0.0f;
        rX[r] = z;
    }
    if (tx == 0) {
        #pragma unroll
        for (int r = 0; r < 8; ++r) { colA[0][I0 + r] = rA[r][0]; colB[0][I0 + r] = rB[r][0]; }
    }
    if (ty == 0) {
        #pragma unroll
        for (int e = 0; e < 4; ++e) rowX[0][J0 + e] = rX[0][e];
    }
    __syncthreads();

    for (int k = 0; k < 127; ++k) {
        const int b = k & 1;
        const float dK = colA[b][k], dG = colB[b][k];
        const float rdK = 1.0f / dK, rdG = 1.0f / dG;
        if (tid == 0) { sDk[k] = dK; sDg[k] = dG; }

        f32x4 caj = *(const f32x4*)&colA[b][J0];
        f32x4 cbj = *(const f32x4*)&colB[b][J0];
        const f32x4 xj = *(const f32x4*)&rowX[b][J0];
        #pragma unroll
        for (int e = 0; e < 4; ++e)
            if (J0 + e <= k) { caj[e] = 0.0f; cbj[e] = 0.0f; }

        f32x4 ca0 = *(const f32x4*)&colA[b][I0];
        f32x4 ca1 = *(const f32x4*)&colA[b][I0 + 4];
        f32x4 cb0 = *(const f32x4*)&colB[b][I0];
        f32x4 cb1 = *(const f32x4*)&colB[b][I0 + 4];
        #pragma unroll
        for (int r = 0; r < 4; ++r) {
            if (I0 + r <= k)     { ca0[r] = 0.0f; cb0[r] = 0.0f; }
            if (I0 + 4 + r <= k) { ca1[r] = 0.0f; cb1[r] = 0.0f; }
        }

        if (I0 + 7 > k) {
            #pragma unroll
            for (int r = 0; r < 8; ++r) {
                const float am = (r < 4) ? ca0[r & 3] : ca1[r & 3];
                const float bm = (r < 4) ? cb0[r & 3] : cb1[r & 3];
                const float fA = am * rdK;
                const float fB = bm * rdG;
                rA[r] -= fA * caj;
                rB[r] -= fB * cbj;
                rX[r] -= fA * xj;
            }
        }

        const int kn = k + 1, bn = kn & 1;
        if (tx == (kn >> 2)) {
            const int es = kn & 3;
            #pragma unroll
            for (int ee = 0; ee < 4; ++ee) if (ee == es) {
                #pragma unroll
                for (int r = 0; r < 8; ++r) {
                    colA[bn][I0 + r] = rA[r][ee];
                    colB[bn][I0 + r] = rB[r][ee];
                }
            }
        }
        if (ty == (kn >> 3)) {
            const int rs = kn & 7;
            #pragma unroll
            for (int rr = 0; rr < 8; ++rr) if (rr == rs) {
                #pragma unroll
                for (int e = 0; e < 4; ++e) rowX[bn][J0 + e] = rX[rr][e];
            }
        }
        __syncthreads();
    }
    if (tid == 511) { sDk[127] = rA[7][3]; sDg[127] = rB[7][3]; }

    // dump X -> LDS (no global round-trip)
    #pragma unroll
    for (int r = 0; r < 8; ++r)
        *(f32x4*)&LX[(I0 + r) * 132 + J0] = rX[r];
    __syncthreads();

    // srd + logdet partials
    if (tid < 128) {
        srd[tid] = 1.0f / sDk[tid];
        float lk = logf(sDk[tid]);
        float lg = logf(sDg[tid]);
        #pragma unroll
        for (int o = 32; o > 0; o >>= 1) { lk += __shfl_xor(lk, o, 64); lg += __shfl_xor(lg, o, 64); }
        if ((tid & 63) == 0) { sRed[(tid >> 6) * 2] = lk; sRed[(tid >> 6) * 2 + 1] = lg; }
    }
    __syncthreads();

    // ---- P2: LM = M1 = X^T D^-1 X  (xa: ty-broadcast b128; xb: coalesced) ----
    {
        f32x4 acc[8] = {};
        for (int k = 0; k < 128; ++k) {
            f32x4 xb = *(const f32x4*)&LX[k * 132 + J0];
            xb *= srd[k];
            const f32x4 xa0 = *(const f32x4*)&LX[k * 132 + I0];
            const f32x4 xa1 = *(const f32x4*)&LX[k * 132 + I0 + 4];
            #pragma unroll
            for (int r = 0; r < 4; ++r) {
                acc[r]     += xa0[r] * xb;
                acc[r + 4] += xa1[r] * xb;
            }
        }
        #pragma unroll
        for (int r = 0; r < 8; ++r)
            *(f32x4*)&LM[(I0 + r) * 132 + J0] = acc[r];

        // trace partial: own M1 tile (regs) o own G tile (own-written global)
        float tr = 0.0f;
        #pragma unroll
        for (int r = 0; r < 8; ++r) {
            const f32x4 g = *(const f32x4*)&out[(I0 + r) * 128 + J0];
            tr += acc[r][0]*g[0] + acc[r][1]*g[1] + acc[r][2]*g[2] + acc[r][3]*g[3];
        }
        #pragma unroll
        for (int o = 32; o > 0; o >>= 1) tr += __shfl_xor(tr, o, 64);
        if ((tid & 63) == 0) sTr[tid >> 6] = tr;
    }
    __syncthreads();   // LM ready; all LX reads done

    // ---- P3: Y = G*M1 -> LX ; Wt bf16 ----
    {
        f32x4 yacc[8] = {};
        for (int mb = 0; mb < 128; mb += 4) {
            f32x4 g4[8];
            #pragma unroll
            for (int r = 0; r < 8; ++r)
                g4[r] = *(const f32x4*)&out[(I0 + r) * 128 + mb];   // 2-addr/wave, L1/L2-hot
            #pragma unroll
            for (int e = 0; e < 4; ++e) {
                const f32x4 mrow = *(const f32x4*)&LM[(mb + e) * 132 + J0];
                #pragma unroll
                for (int r = 0; r < 8; ++r)
                    yacc[r] += g4[r][e] * mrow;
            }
        }
        #pragma unroll
        for (int r = 0; r < 8; ++r) {
            *(f32x4*)&LX[(I0 + r) * 132 + J0] = yacc[r];
            const int c = I0 + r;                      // Wt[c][k] = Y[c][k]
            const uint32_t lo = (uint32_t)f2bf(yacc[r][0]) | ((uint32_t)f2bf(yacc[r][1]) << 16);
            const uint32_t hi = (uint32_t)f2bf(yacc[r][2]) | ((uint32_t)f2bf(yacc[r][3]) << 16);
            const uint32_t byteoff = (uint32_t)((c * 256 + J0 * 2) ^ ((c & 7) << 4));
            *(uint2*)(wsb + byteoff) = make_uint2(lo, hi);
        }
    }
    __syncthreads();   // LX now holds Y

    // ---- P4: Q = M1*Y - M1 -> Qt bf16 ----
    {
        f32x4 qacc[8];
        #pragma unroll
        for (int r = 0; r < 8; ++r)
            qacc[r] = - *(const f32x4*)&LM[(I0 + r) * 132 + J0];
        for (int mb = 0; mb < 128; mb += 4) {
            f32x4 m4[8];
            #pragma unroll
            for (int r = 0; r < 8; ++r)
                m4[r] = *(const f32x4*)&LM[(I0 + r) * 132 + mb];    // ty-broadcast b128
            #pragma unroll
            for (int e = 0; e < 4; ++e) {
                const f32x4 yrow = *(const f32x4*)&LX[(mb + e) * 132 + J0];
                #pragma unroll
                for (int r = 0; r < 8; ++r)
                    qacc[r] += m4[r][e] * yrow;
            }
        }
        #pragma unroll
        for (int r = 0; r < 8; ++r) {
            const int c = I0 + r;
            const uint32_t lo = (uint32_t)f2bf(qacc[r][0]) | ((uint32_t)f2bf(qacc[r][1]) << 16);
            const uint32_t hi = (uint32_t)f2bf(qacc[r][2]) | ((uint32_t)f2bf(qacc[r][3]) << 16);
            const uint32_t byteoff = (uint32_t)((c * 256 + J0 * 2) ^ ((c & 7) << 4));
            *(uint2*)(wsb + 32768 + byteoff) = make_uint2(lo, hi);
        }
    }

    // ---- obj ----
    __syncthreads();
    if (tid == 0) {
        float trace = 0.0f;
        #pragma unroll
        for (int i = 0; i < 8; ++i) trace += sTr[i];
        const float ldK = sRed[0] + sRed[2];
        const float ldG = sRed[1] + sRed[3];
        const float dof = (float)dofp[0];
        out[67649536] = -0.5f * dof * (-(ldG - ldK) + trace - 128.0f);
    }
}

// ---------------------------------------------------------------------------
// main: Gti = T*W, gt = tt + rowsum((T*Q) o T).  (verbatim R4 winner, ~175us)
// 256 rows/block, 512 threads (8 waves), 2048 blocks, 64KB LDS.
// ---------------------------------------------------------------------------
__global__ __launch_bounds__(512) void main_kernel(
    const float* __restrict__ Kti, const float* __restrict__ Kt,
    const float* __restrict__ ws, float* __restrict__ Gti,
    float* __restrict__ gt)
{
    __shared__ __align__(16) char smem[65536];   // Wt|Qt bf16 swizzled image
    const int tid = threadIdx.x;
    const int lane = tid & 63, wid = tid >> 6;
    const int l15 = lane & 15, l4 = lane >> 4;
    const int brow = blockIdx.x * 256;
    const int wrow = wid * 32;

    const float* tbase = Kti + (size_t)(brow + wrow + l15) * 128;

    // 1) issue ALL 16 T-loads (256 B/lane in flight, one vmcnt drain)
    f32x4 t[4][4];
    #pragma unroll
    for (int kc = 0; kc < 4; ++kc) {
        const float* p0 = tbase + kc * 32 + l4 * 8;
        const float* p1 = p0 + 16 * 128;
        t[kc][0] = *(const f32x4*)p0;
        t[kc][1] = *(const f32x4*)(p0 + 4);
        t[kc][2] = *(const f32x4*)p1;
        t[kc][3] = *(const f32x4*)(p1 + 4);
    }

    // 2) stage ws -> LDS (L2/L3-hot), 128 B/thread
    {
        f32x4* s4 = (f32x4*)smem;
        const f32x4* w4 = (const f32x4*)ws;
        #pragma unroll
        for (int i = 0; i < 8; ++i) s4[tid + i * 512] = w4[tid + i * 512];
    }

    // 3) convert T to bf16 A-frags (waits the global loads)
    short8 a[4][2];
    #pragma unroll
    for (int kc = 0; kc < 4; ++kc) {
        a[kc][0] = { (short)f2bf(t[kc][0][0]), (short)f2bf(t[kc][0][1]), (short)f2bf(t[kc][0][2]), (short)f2bf(t[kc][0][3]),
                     (short)f2bf(t[kc][1][0]), (short)f2bf(t[kc][1][1]), (short)f2bf(t[kc][1][2]), (short)f2bf(t[kc][1][3]) };
        a[kc][1] = { (short)f2bf(t[kc][2][0]), (short)f2bf(t[kc][2][1]), (short)f2bf(t[kc][2][2]), (short)f2bf(t[kc][2][3]),
                     (short)f2bf(t[kc][3][0]), (short)f2bf(t[kc][3][1]), (short)f2bf(t[kc][3][2]), (short)f2bf(t[kc][3][3]) };
    }
    __syncthreads();

    // 4) uninterrupted 128-MFMA stream
    f32x4 accW[2][8] = {};
    f32x4 accZ[2][8] = {};
    #pragma unroll
    for (int kc = 0; kc < 4; ++kc) {
        const int k0 = kc * 32 + l4 * 8;
        #pragma unroll
        for (int ct = 0; ct < 8; ++ct) {
            const int c = ct * 16 + l15;
            const int byteoff = (c * 256 + k0 * 2) ^ ((c & 7) << 4);
            const short8 bW = *(const short8*)(smem + byteoff);
            const short8 bQ = *(const short8*)(smem + 32768 + byteoff);
            accW[0][ct] = __builtin_amdgcn_mfma_f32_16x16x32_bf16(a[kc][0], bW, accW[0][ct], 0, 0, 0);
            accW[1][ct] = __builtin_amdgcn_mfma_f32_16x16x32_bf16(a[kc][1], bW, accW[1][ct], 0, 0, 0);
            accZ[0][ct] = __builtin_amdgcn_mfma_f32_16x16x32_bf16(a[kc][0], bQ, accZ[0][ct], 0, 0, 0);
            accZ[1][ct] = __builtin_amdgcn_mfma_f32_16x16x32_bf16(a[kc][1], bQ, accZ[1][ct], 0, 0, 0);
        }
    }

    // 5) gt epilogue (C/D layout: col=l15, row=l4*4+r); trow re-reads L1/L2-hot
    #pragma unroll
    for (int rt = 0; rt < 2; ++rt) {
        #pragma unroll
        for (int r = 0; r < 4; ++r) {
            const int row = brow + wrow + rt * 16 + l4 * 4 + r;
            const float* trow = Kti + (size_t)row * 128;
            float p = 0.0f;
            #pragma unroll
            for (int ct = 0; ct < 8; ++ct) p += accZ[rt][ct][r] * trow[ct * 16 + l15];
            p += __shfl_xor(p, 1, 64);
            p += __shfl_xor(p, 2, 64);
            p += __shfl_xor(p, 4, 64);
            p += __shfl_xor(p, 8, 64);
            if (l15 == 0) gt[row] = Kt[row] + p;
        }
    }

    // 6) direct Gti stores from accW (16-lane / 64B coalesced granules)
    #pragma unroll
    for (int rt = 0; rt < 2; ++rt) {
        #pragma unroll
        for (int r = 0; r < 4; ++r) {
            float* grow = Gti + (size_t)(brow + wrow + rt * 16 + l4 * 4 + r) * 128 + l15;
            #pragma unroll
            for (int ct = 0; ct < 8; ++ct)
                grow[ct * 16] = accW[rt][ct][r];
        }
    }
}

extern "C" void kernel_launch(void* const* d_in, const int* in_sizes, int n_in,
                              void* d_out, int out_size, void* d_ws, size_t ws_size,
                              hipStream_t stream)
{
    const float* Kii = (const float*)d_in[0];
    const float* Kti = (const float*)d_in[1];
    const float* Kt  = (const float*)d_in[2];
    const float* V   = (const float*)d_in[3];
    const float* gs  = (const float*)d_in[4];
    const int*   dof = (const int*)d_in[5];
    float* out = (float*)d_out;
    float* ws  = (float*)d_ws;

    const int N = in_sizes[2];          // 524288
    const int nblocks = N / 256;        // 2048

    kS2_setup<<<1, 512, 0, stream>>>(Kii, V, gs, dof, out, (char*)ws);
    main_kernel<<<nblocks, 512, 0, stream>>>(Kti, Kt, ws,
                                             out + 16384,          // Gti
                                             out + 67125248);      // gt
}

// Round 15
// 311.884 us; speedup vs baseline: 1.8987x; 1.1205x over previous
//
#include <hip/hip_runtime.h>
#include <cstdint>

typedef __attribute__((ext_vector_type(8))) short short8;
typedef __attribute__((ext_vector_type(4))) float f32x4;

__device__ __forceinline__ unsigned short f2bf(float f) {
    uint32_t u = __builtin_bit_cast(uint32_t, f);
    u += 0x7FFFu + ((u >> 16) & 1u);   // round-to-nearest-even
    return (unsigned short)(u >> 16);
}

// out float offsets: Gii 0, Gti 16384, gt 67125248, obj 67649536
// fp32 scratch INSIDE the Gti region (overwritten later by main):
#define SG_OFF   16384     // G fp32 [128][128]
#define SM1_OFF  32768     // M1 = Kii^-1
#define SY_OFF   49152     // Y = G*M1
#define SX_OFF   65536     // X = Lunit^-1 (unit lower, upper zeros)
#define SD_OFF   81920     // d[0..127], [128]=logdetK, [129]=logdetG, [132+bid]=trace partials
// ws bytes [0,32768) = Wt bf16 swizzled; [32768,65536) = Qt bf16 swizzled
// swizzle: byte = (c*256 + k*2) ^ ((c&7)<<4)

// ---------------------------------------------------------------------------
// k0: G = V V^T /128 * e^s  -> out[0..16K) (Gii) and scratch sG. 16 blocks.
// ---------------------------------------------------------------------------
__global__ __launch_bounds__(256) void k0_G(
    const float* __restrict__ V, const float* __restrict__ gs,
    float* __restrict__ out)
{
    float* sG = out + SG_OFF;
    const float egs = expf(gs[0]) * (1.0f / 128.0f);
    const int ty = threadIdx.x >> 5, tx = threadIdx.x & 31;
    const int r = blockIdx.x * 8 + ty;
    const f32x4* V4 = (const f32x4*)V;
    f32x4 acc = {0.f, 0.f, 0.f, 0.f};
    for (int kq = 0; kq < 32; ++kq) {
        const f32x4 vr = V4[r * 32 + kq];
        #pragma unroll
        for (int e = 0; e < 4; ++e) {
            const f32x4 vc = V4[(tx * 4 + e) * 32 + kq];
            acc[e] += vr[0]*vc[0] + vr[1]*vc[1] + vr[2]*vc[2] + vr[3]*vc[3];
        }
    }
    acc *= egs;
    *(f32x4*)&out[r * 128 + tx * 4] = acc;
    *(f32x4*)&sG[r * 128 + tx * 4] = acc;
}

// ---------------------------------------------------------------------------
// k1b: BLOCKED dual factor, 2 blocks x 512 threads (K and G on separate CUs).
// Panel width 16, 8 panels, 4 barriers/panel (vs 127 barriers unblocked).
// block 0 (K): register-tile LDL^T + integrated blocked X = Lunit^-1;
//              writes X->SX_OFF, d->SD[0..127], logdetK->SD[128].
// block 1 (G): same factor minus X; logdetG->SD[129].
// Same recurrence as the proven column loop, blocked order:
//   A[i][j] -= A[i][m] * A[j][m] * (1/d[m]) for panels m=kb..kb+15.
// LDS: PR raw panel [128][17]; PS scaled panel [128][17] (row-broadcast reads);
//      PRT scaled^T... PRT raw-transposed [16][132] (b128 j-side reads);
//      XP X panel rows [16][132].
// ---------------------------------------------------------------------------
__global__ __launch_bounds__(512, 2) void k1b_factor(
    const float* __restrict__ Kii, float* __restrict__ out)
{
    __shared__ float PR[128 * 17];
    __shared__ float PS[128 * 17];
    __shared__ float PRT[16 * 132];
    __shared__ float XP[16 * 132];
    __shared__ float sD[128], sRed[2];

    const int tid = threadIdx.x;
    const int wv = tid >> 6;
    const int lane = tid & 63;
    const int ty = tid >> 5, tx = tid & 31;
    const int I0 = ty * 8, J0 = tx * 4;
    const bool isK = (blockIdx.x == 0);
    const float* src = isK ? Kii : (out + SG_OFF);
    float* dbuf = out + SD_OFF;

    f32x4 rA[8], rX[8];
    #pragma unroll
    for (int r = 0; r < 8; ++r) {
        rA[r] = *(const f32x4*)&src[(size_t)(I0 + r) * 128 + J0];
        f32x4 z = {0.f, 0.f, 0.f, 0.f};
        #pragma unroll
        for (int e = 0; e < 4; ++e) z[e] = (I0 + r == J0 + e) ? 1.0f : 0.0f;
        rX[r] = z;
    }

    for (int kb = 0; kb < 128; kb += 16) {
        // ---- P1: publish raw panel cols (owners) + X panel rows (K only) ----
        if (J0 >= kb && J0 < kb + 16) {
            const int c0 = J0 - kb;
            #pragma unroll
            for (int r = 0; r < 8; ++r) {
                #pragma unroll
                for (int e = 0; e < 4; ++e)
                    PR[(I0 + r) * 17 + c0 + e] = rA[r][e];
            }
        }
        if (isK && I0 >= kb && I0 < kb + 16) {
            #pragma unroll
            for (int r = 0; r < 8; ++r)
                *(f32x4*)&XP[(I0 + r - kb) * 132 + J0] = rX[r];
        }
        __syncthreads();

        // ---- P2a: wave 0 factors the 16x16 diag block in-wave ----
        if (wv == 0) {
            const int di = lane & 15;
            const int m4 = (lane >> 4) * 4;
            #pragma unroll
            for (int p = 0; p < 16; ++p) {
                const float d = PR[(kb + p) * 17 + p];
                if (lane == 0) sD[kb + p] = d;
                const float rdp = 1.0f / d;
                const float aip = PR[(kb + di) * 17 + p];
                float pm[4];
                #pragma unroll
                for (int e = 0; e < 4; ++e) pm[e] = PR[(kb + p) * 17 + m4 + e];
                #pragma unroll
                for (int e = 0; e < 4; ++e)
                    if (di > p && (m4 + e) > p)
                        PR[(kb + di) * 17 + m4 + e] -= aip * pm[e] * rdp;
            }
        }
        __syncthreads();

        // ---- P2b ----
        if (wv < 2) {
            // panel solve, rows kb+16..127: pr[j] -= sum_{m<j} pr[m]*Ldiag[j][m]
            const int i = kb + 16 + wv * 64 + lane;
            if (i < 128) {
                float rdv[16], pr[16];
                #pragma unroll
                for (int m = 0; m < 16; ++m) {
                    rdv[m] = 1.0f / sD[kb + m];
                    pr[m] = PR[i * 17 + m];
                }
                #pragma unroll
                for (int j = 1; j < 16; ++j) {
                    #pragma unroll
                    for (int m = 0; m < 16; ++m)
                        if (m < j)
                            pr[j] -= pr[m] * PR[(kb + j) * 17 + m] * rdv[m];
                }
                #pragma unroll
                for (int m = 0; m < 16; ++m) {
                    PR[i * 17 + m] = pr[m];
                    PRT[m * 132 + i] = pr[m];
                    PS[i * 17 + m] = pr[m] * rdv[m];
                }
            }
        } else if (wv == 2 && isK) {
            // X panel intra-update: row kb+p -= sum_{m<p} Lunit[kb+p][kb+m]*row kb+m
            const int c0 = lane * 2;
            #pragma unroll
            for (int p = 1; p < 16; ++p) {
                float x0 = XP[p * 132 + c0], x1 = XP[p * 132 + c0 + 1];
                #pragma unroll
                for (int m = 0; m < 16; ++m) {
                    if (m < p) {
                        const float f = PR[(kb + p) * 17 + m] * (1.0f / sD[kb + m]);
                        x0 -= f * XP[m * 132 + c0];
                        x1 -= f * XP[m * 132 + c0 + 1];
                    }
                }
                XP[p * 132 + c0] = x0;
                XP[p * 132 + c0 + 1] = x1;
            }
        }
        __syncthreads();

        // ---- P3: register trailing update (rank-16), whole-tile masks ----
        const bool rowOK = (I0 >= kb + 16);
        const bool colOK = (J0 >= kb + 16);
        if (rowOK) {
            #pragma unroll
            for (int m = 0; m < 16; ++m) {
                float si[8];
                #pragma unroll
                for (int r = 0; r < 8; ++r) si[r] = PS[(I0 + r) * 17 + m];
                if (isK) {
                    const f32x4 xv = *(const f32x4*)&XP[m * 132 + J0];
                    #pragma unroll
                    for (int r = 0; r < 8; ++r) rX[r] -= si[r] * xv;
                }
                if (colOK) {
                    const f32x4 cj = *(const f32x4*)&PRT[m * 132 + J0];
                    #pragma unroll
                    for (int r = 0; r < 8; ++r) rA[r] -= si[r] * cj;
                }
            }
        }
        // owners of X panel rows reload final values
        if (isK && I0 >= kb && I0 < kb + 16) {
            #pragma unroll
            for (int r = 0; r < 8; ++r)
                rX[r] = *(const f32x4*)&XP[(I0 + r - kb) * 132 + J0];
        }
        __syncthreads();
    }

    // ---- epilogue ----
    if (isK) {
        float* sXg = out + SX_OFF;
        #pragma unroll
        for (int r = 0; r < 8; ++r)
            *(f32x4*)&sXg[(I0 + r) * 128 + J0] = rX[r];
    }
    if (tid < 128) {
        if (isK) dbuf[tid] = sD[tid];
        float lv = logf(sD[tid]);
        #pragma unroll
        for (int o = 32; o > 0; o >>= 1) lv += __shfl_xor(lv, o, 64);
        if ((tid & 63) == 0) sRed[tid >> 6] = lv;
    }
    __syncthreads();
    if (tid == 0) dbuf[isK ? 128 : 129] = sRed[0] + sRed[1];
}

// ---------------------------------------------------------------------------
// k2: M1 = X^T D^-1 X  (= Kii^-1). 16 blocks.
// ---------------------------------------------------------------------------
__global__ __launch_bounds__(256) void k2_M1(float* __restrict__ out)
{
    const float* sX = out + SX_OFF;
    const float* dbuf = out + SD_OFF;
    float* sM1 = out + SM1_OFF;
    __shared__ float srd[128];
    const int tid = threadIdx.x;
    if (tid < 128) srd[tid] = 1.0f / dbuf[tid];
    __syncthreads();
    const int ty = tid >> 5, tx = tid & 31;
    const int a = blockIdx.x * 8 + ty;
    const f32x4* X4 = (const f32x4*)sX;
    f32x4 acc = {0.f, 0.f, 0.f, 0.f};
    for (int k = a; k < 128; ++k) {          // X[k][a]=0 for k<a
        const float xa = sX[k * 128 + a] * srd[k];
        acc += xa * X4[k * 32 + tx];
    }
    *(f32x4*)&sM1[a * 128 + tx * 4] = acc;
}

// ---------------------------------------------------------------------------
// k3: Y = G*M1 -> scratch + Wt bf16 swizzled; trace partials. 16 blocks.
// ---------------------------------------------------------------------------
__global__ __launch_bounds__(256) void k3_Y(float* __restrict__ out, char* __restrict__ wsb)
{
    const float* sG = out + SG_OFF;
    const float* sM1 = out + SM1_OFF;
    float* sY = out + SY_OFF;
    float* dbuf = out + SD_OFF;
    const int tid = threadIdx.x;
    const int ty = tid >> 5, tx = tid & 31;
    const int c = blockIdx.x * 8 + ty;
    const f32x4* M14 = (const f32x4*)sM1;
    f32x4 acc = {0.f, 0.f, 0.f, 0.f};
    for (int m = 0; m < 128; ++m)
        acc += sG[c * 128 + m] * M14[m * 32 + tx];
    *(f32x4*)&sY[c * 128 + tx * 4] = acc;
    const uint32_t lo = (uint32_t)f2bf(acc[0]) | ((uint32_t)f2bf(acc[1]) << 16);
    const uint32_t hi = (uint32_t)f2bf(acc[2]) | ((uint32_t)f2bf(acc[3]) << 16);
    const uint32_t byteoff = (uint32_t)((c * 256 + tx * 8) ^ ((c & 7) << 4));
    *(uint2*)(wsb + byteoff) = make_uint2(lo, hi);
    float t;
    {
        const f32x4* G4 = (const f32x4*)sG;
        const int idx = blockIdx.x * 256 + tid;
        const f32x4 g = G4[idx], mm = M14[idx];
        t = g[0]*mm[0] + g[1]*mm[1] + g[2]*mm[2] + g[3]*mm[3];
    }
    #pragma unroll
    for (int o = 32; o > 0; o >>= 1) t += __shfl_xor(t, o, 64);
    __shared__ float sp[4];
    if ((tid & 63) == 0) sp[tid >> 6] = t;
    __syncthreads();
    if (tid == 0) dbuf[132 + blockIdx.x] = sp[0] + sp[1] + sp[2] + sp[3];
}

// ---------------------------------------------------------------------------
// k4: Q = M1*Y - M1 -> Qt bf16 swizzled; finalize obj. 16 blocks.
// ---------------------------------------------------------------------------
__global__ __launch_bounds__(256) void k4_Q(
    float* __restrict__ out, char* __restrict__ wsb, const int* __restrict__ dofp)
{
    const float* sM1 = out + SM1_OFF;
    const float* sY = out + SY_OFF;
    const float* dbuf = out + SD_OFF;
    const int tid = threadIdx.x;
    const int ty = tid >> 5, tx = tid & 31;
    const int c = blockIdx.x * 8 + ty;
    const f32x4* Y4 = (const f32x4*)sY;
    const f32x4* M14 = (const f32x4*)sM1;
    f32x4 acc = -M14[c * 32 + tx];
    for (int m = 0; m < 128; ++m)
        acc += sM1[c * 128 + m] * Y4[m * 32 + tx];
    const uint32_t lo = (uint32_t)f2bf(acc[0]) | ((uint32_t)f2bf(acc[1]) << 16);
    const uint32_t hi = (uint32_t)f2bf(acc[2]) | ((uint32_t)f2bf(acc[3]) << 16);
    const uint32_t byteoff = (uint32_t)((c * 256 + tx * 8) ^ ((c & 7) << 4));
    *(uint2*)(wsb + 32768 + byteoff) = make_uint2(lo, hi);
    if (blockIdx.x == 0 && tid == 0) {
        float trace = 0.0f;
        for (int i = 0; i < 16; ++i) trace += dbuf[132 + i];
        const float ldK = dbuf[128], ldG = dbuf[129];
        const float dof = (float)dofp[0];
        out[67649536] = -0.5f * dof * (-(ldG - ldK) + trace - 128.0f);
    }
}

// ---------------------------------------------------------------------------
// main: Gti = T*W, gt = tt + rowsum((T*Q) o T).  (verbatim R4 winner, ~175us)
// 256 rows/block, 512 threads (8 waves), 2048 blocks, 64KB LDS.
// ---------------------------------------------------------------------------
__global__ __launch_bounds__(512) void main_kernel(
    const float* __restrict__ Kti, const float* __restrict__ Kt,
    const float* __restrict__ ws, float* __restrict__ Gti,
    float* __restrict__ gt)
{
    __shared__ __align__(16) char smem[65536];   // Wt|Qt bf16 swizzled image
    const int tid = threadIdx.x;
    const int lane = tid & 63, wid = tid >> 6;
    const int l15 = lane & 15, l4 = lane >> 4;
    const int brow = blockIdx.x * 256;
    const int wrow = wid * 32;

    const float* tbase = Kti + (size_t)(brow + wrow + l15) * 128;

    // 1) issue ALL 16 T-loads (256 B/lane in flight, one vmcnt drain)
    f32x4 t[4][4];
    #pragma unroll
    for (int kc = 0; kc < 4; ++kc) {
        const float* p0 = tbase + kc * 32 + l4 * 8;
        const float* p1 = p0 + 16 * 128;
        t[kc][0] = *(const f32x4*)p0;
        t[kc][1] = *(const f32x4*)(p0 + 4);
        t[kc][2] = *(const f32x4*)p1;
        t[kc][3] = *(const f32x4*)(p1 + 4);
    }

    // 2) stage ws -> LDS (L2/L3-hot), 128 B/thread
    {
        f32x4* s4 = (f32x4*)smem;
        const f32x4* w4 = (const f32x4*)ws;
        #pragma unroll
        for (int i = 0; i < 8; ++i) s4[tid + i * 512] = w4[tid + i * 512];
    }

    // 3) convert T to bf16 A-frags (waits the global loads)
    short8 a[4][2];
    #pragma unroll
    for (int kc = 0; kc < 4; ++kc) {
        a[kc][0] = { (short)f2bf(t[kc][0][0]), (short)f2bf(t[kc][0][1]), (short)f2bf(t[kc][0][2]), (short)f2bf(t[kc][0][3]),
                     (short)f2bf(t[kc][1][0]), (short)f2bf(t[kc][1][1]), (short)f2bf(t[kc][1][2]), (short)f2bf(t[kc][1][3]) };
        a[kc][1] = { (short)f2bf(t[kc][2][0]), (short)f2bf(t[kc][2][1]), (short)f2bf(t[kc][2][2]), (short)f2bf(t[kc][2][3]),
                     (short)f2bf(t[kc][3][0]), (short)f2bf(t[kc][3][1]), (short)f2bf(t[kc][3][2]), (short)f2bf(t[kc][3][3]) };
    }
    __syncthreads();

    // 4) uninterrupted 128-MFMA stream
    f32x4 accW[2][8] = {};
    f32x4 accZ[2][8] = {};
    #pragma unroll
    for (int kc = 0; kc < 4; ++kc) {
        const int k0 = kc * 32 + l4 * 8;
        #pragma unroll
        for (int ct = 0; ct < 8; ++ct) {
            const int c = ct * 16 + l15;
            const int byteoff = (c * 256 + k0 * 2) ^ ((c & 7) << 4);
            const short8 bW = *(const short8*)(smem + byteoff);
            const short8 bQ = *(const short8*)(smem + 32768 + byteoff);
            accW[0][ct] = __builtin_amdgcn_mfma_f32_16x16x32_bf16(a[kc][0], bW, accW[0][ct], 0, 0, 0);
            accW[1][ct] = __builtin_amdgcn_mfma_f32_16x16x32_bf16(a[kc][1], bW, accW[1][ct], 0, 0, 0);
            accZ[0][ct] = __builtin_amdgcn_mfma_f32_16x16x32_bf16(a[kc][0], bQ, accZ[0][ct], 0, 0, 0);
            accZ[1][ct] = __builtin_amdgcn_mfma_f32_16x16x32_bf16(a[kc][1], bQ, accZ[1][ct], 0, 0, 0);
        }
    }

    // 5) gt epilogue (C/D layout: col=l15, row=l4*4+r); trow re-reads L1/L2-hot
    #pragma unroll
    for (int rt = 0; rt < 2; ++rt) {
        #pragma unroll
        for (int r = 0; r < 4; ++r) {
            const int row = brow + wrow + rt * 16 + l4 * 4 + r;
            const float* trow = Kti + (size_t)row * 128;
            float p = 0.0f;
            #pragma unroll
            for (int ct = 0; ct < 8; ++ct) p += accZ[rt][ct][r] * trow[ct * 16 + l15];
            p += __shfl_xor(p, 1, 64);
            p += __shfl_xor(p, 2, 64);
            p += __shfl_xor(p, 4, 64);
            p += __shfl_xor(p, 8, 64);
            if (l15 == 0) gt[row] = Kt[row] + p;
        }
    }

    // 6) direct Gti stores from accW (16-lane / 64B coalesced granules)
    #pragma unroll
    for (int rt = 0; rt < 2; ++rt) {
        #pragma unroll
        for (int r = 0; r < 4; ++r) {
            float* grow = Gti + (size_t)(brow + wrow + rt * 16 + l4 * 4 + r) * 128 + l15;
            #pragma unroll
            for (int ct = 0; ct < 8; ++ct)
                grow[ct * 16] = accW[rt][ct][r];
        }
    }
}

extern "C" void kernel_launch(void* const* d_in, const int* in_sizes, int n_in,
                              void* d_out, int out_size, void* d_ws, size_t ws_size,
                              hipStream_t stream)
{
    const float* Kii = (const float*)d_in[0];
    const float* Kti = (const float*)d_in[1];
    const float* Kt  = (const float*)d_in[2];
    const float* V   = (const float*)d_in[3];
    const float* gs  = (const float*)d_in[4];
    const int*   dof = (const int*)d_in[5];
    float* out = (float*)d_out;
    float* ws  = (float*)d_ws;

    const int N = in_sizes[2];          // 524288
    const int nblocks = N / 256;        // 2048

    k0_G<<<16, 256, 0, stream>>>(V, gs, out);
    k1b_factor<<<2, 512, 0, stream>>>(Kii, out);
    k2_M1<<<16, 256, 0, stream>>>(out);
    k3_Y<<<16, 256, 0, stream>>>(out, (char*)ws);
    k4_Q<<<16, 256, 0, stream>>>(out, (char*)ws, dof);
    main_kernel<<<nblocks, 512, 0, stream>>>(Kti, Kt, ws,
                                             out + 16384,          // Gti
                                             out + 67125248);      // gt
}